// Round 12
// baseline (222.097 us; speedup 1.0000x reference)
//
#include <hip/hip_runtime.h>
#include <hip/hip_bf16.h>

// ---------------- sizes ----------------
#define BB 32
#define TW 40
#define NN 50
#define HH 128
#define CO 64
#define EE 800
#define TT 38      // Tw - 2
#define TT2 36     // TT - 2
#define TPOOL 34   // TT2 - 2
#define NCO 3200   // N*Co
#define SS (BB*TT)     // 1216 graphs
#define NPAD 64
#define RPAD (SS*NPAD)

// fragment-major G plane: addr(node,feat) = g*8192 + (node>>5)*4096 + (feat>>4)*512
//                                         + ((feat>>3)&1)*256 + (node&31)*8 + (feat&7)
#define PB_US ((size_t)RPAD * HH)
#define PB_BYTES (PB_US * 2)          // 19,922,944

typedef __attribute__((ext_vector_type(8))) short s16x8;
typedef __attribute__((ext_vector_type(16))) float f32x16;
typedef unsigned short us;

static __device__ __forceinline__ unsigned int f2bf_u(float x) {
    unsigned int u = __float_as_uint(x);
    return (u + 0x7fffu + ((u >> 16) & 1u)) >> 16;
}
static __device__ __forceinline__ float bfu2f(unsigned int h) {
    return __uint_as_float(h << 16);
}
static __device__ __forceinline__ size_t fragoff32(int m, int c) {  // m<32
    return (size_t)(c >> 4) * 512 + ((c >> 3) & 1) * 256 + m * 8 + (c & 7);
}
#define MFMA(a, b, c) __builtin_amdgcn_mfma_f32_32x32x16_bf16((a), (b), (c), 0, 0, 0)

// ---------------- kernel 1: weight prep + zero pooled accumulator ----------------
__global__ __launch_bounds__(256) void k_wprep(
    const float* __restrict__ cw,
    const float* __restrict__ tw1, const float* __restrict__ tw2, const float* __restrict__ tw3,
    us* __restrict__ VTh, us* __restrict__ VTl,
    us* __restrict__ WTh,
    float* __restrict__ pooled)
{
    int idx = blockIdx.x * 256 + threadIdx.x;
    float v; int col, k; bool wantlo;
    us *dh, *dl;
    if (idx < 128 * 384) {
        col = idx / 384; k = idx % 384;
        if (k < 128)      v = cw[k * 128 + col] - cw[32768 + k * 128 + col];
        else if (k < 256) v = cw[16384 + (k - 128) * 128 + col];
        else              v = 2.f * cw[32768 + (k - 256) * 128 + col];
        dh = VTh; dl = VTl; wantlo = true;
    } else if (idx < 128 * 384 + 192 * 384) {
        int i2 = idx - 128 * 384;
        col = i2 / 384; k = i2 % 384;
        int gg = col >> 6, o = col & 63;
        const float* src = (gg == 0) ? tw1 : (gg == 1) ? tw2 : tw3;
        v = src[k * 64 + o];
        dh = WTh; dl = 0; wantlo = false;
    } else {
        int z = idx - (128 * 384 + 192 * 384);
        if (z < 4096) pooled[z] = 0.f;
        return;
    }
    size_t off = ((size_t)((col >> 5) * 24 + (k >> 4)) * 64 + ((k >> 3) & 1) * 32 + (col & 31)) * 8
               + (k & 7);
    unsigned int h = f2bf_u(v);
    dh[off] = (us)h;
    if (wantlo) dl[off] = (us)f2bf_u(v - bfu2f(h));
}

// ---------------- kernel 2: fused tconv1 + Cheb prop + einsum, one block/graph ----------
// (unchanged from round 11 — measured 50 µs)
#define TAS 136
#define TBS 72
#define LMS 53
__global__ __launch_bounds__(256) void k_cheb(
    const int* __restrict__ EI, const float* __restrict__ X,
    const float* __restrict__ w1, const float* __restrict__ b1,
    const float* __restrict__ w2, const float* __restrict__ b2,
    const float* __restrict__ w3, const float* __restrict__ b3,
    const us* __restrict__ VTh, const us* __restrict__ VTl,
    const float* __restrict__ bias,
    us* __restrict__ Gh)
{
    __shared__ __align__(16) char smem[61440];
    us* TbA = (us*)smem;                       // 64*136 us
    us* TbB = (us*)(smem + 17408);             // 128*72 us (T0-B, then P1-B)
    us* Pa  = (us*)(smem + 35840);             // 64*136 us (P1-A, then P2-A)
    float* Lm = (float*)(smem + 35840);        // 52*53 f32 overlay
    us* LA  = (us*)(smem + 53248);             // 4096 us
    float* Xs = (float*)(smem + 53248);        // 300 f overlay
    int* deg  = (int*)(smem + 53248 + 1216);
    float* dis = (float*)(smem + 53248 + 1216 + 224);

    int g = blockIdx.x;
    int tid = threadIdx.x;
    int b = g / TT, t = g % TT;
    const int* row = EI + (size_t)(b * TW + t) * 2 * EE;
    const int* col = row + EE;

    {
        s16x8 zz = {0, 0, 0, 0, 0, 0, 0, 0};
        for (int i = tid; i < 2240; i += 256) ((s16x8*)smem)[i] = zz;
    }
    for (int i = tid; i < 52 * LMS; i += 256) Lm[i] = 0.f;
    for (int i = tid; i < 300; i += 256) Xs[i] = X[(size_t)(b * TW + t) * 100 + i];
    if (tid < NN) deg[tid] = 0;
    __syncthreads();

    {
        int c = tid & 127, nh = tid >> 7;
        float wr1[6], wr2[6], wr3[6];
#pragma unroll
        for (int q = 0; q < 6; q++) {
            wr1[q] = w1[q * HH + c];
            wr2[q] = w2[q * HH + c];
            wr3[q] = w3[q * HH + c];
        }
        float bv1 = b1[c], bv2 = b2[c], bv3 = b3[c];
        for (int n = nh; n < NN; n += 2) {
            float P = bv1, Q = bv2, R = bv3;
#pragma unroll
            for (int q = 0; q < 6; q++) {
                float x = Xs[(q >> 1) * 100 + n * 2 + (q & 1)];
                P += x * wr1[q]; Q += x * wr2[q]; R += x * wr3[q];
            }
            float sg = 1.f / (1.f + expf(-Q));
            float v = P * sg + R;
            v = v > 0.f ? v : 0.f;
            us h = (us)f2bf_u(v);
            TbA[n * TAS + c] = h;
            TbB[c * TBS + n] = h;
        }
    }
    __syncthreads();
    for (int e = tid; e < EE; e += 256) atomicAdd(&deg[row[e]], 1);
    __syncthreads();
    if (tid < NN) dis[tid] = deg[tid] > 0 ? rsqrtf((float)deg[tid]) : 0.f;
    __syncthreads();
    for (int e = tid; e < EE; e += 256) {
        int r = row[e], cc = col[e];
        atomicAdd(&Lm[r * LMS + cc], -dis[r] * dis[cc]);
    }
    __syncthreads();
    for (int ent = tid; ent < 512; ent += 256) {
        int lanee = ent & 63;
        int ks = (ent >> 6) & 3;
        int mt = ent >> 8;
        int m = mt * 32 + (lanee & 31);
        int kb = ks * 16 + (lanee >> 5) * 8;
        s16x8 v;
#pragma unroll
        for (int j = 0; j < 8; j++) {
            int k = kb + j;
            float lv = (m < NN && k < NN) ? Lm[m * LMS + k] : 0.f;
            v[j] = (short)f2bf_u(lv);
        }
        *(s16x8*)(LA + ent * 8) = v;
    }
    __syncthreads();

    int lane = tid & 63;
    int w = tid >> 6;
    int rg = w >> 1, fh = w & 1;
    int nl = lane & 31;
    int khalf = lane >> 5;
    size_t laneoff = (size_t)lane * 8;

    const us* vh0 = VTh + (size_t)(fh * 2) * 12288 + laneoff;
    const us* vh1 = VTh + (size_t)(fh * 2 + 1) * 12288 + laneoff;
    const us* vl0 = VTl + (size_t)(fh * 2) * 12288 + laneoff;
    const us* vl1 = VTl + (size_t)(fh * 2 + 1) * 12288 + laneoff;

    int mrowA = rg * 32 + nl;
    int kbb = khalf * 8;

    f32x16 gacc0, gacc1, d0, d1;
#pragma unroll
    for (int r = 0; r < 16; r++) { gacc0[r] = 0.f; gacc1[r] = 0.f; d0[r] = 0.f; d1[r] = 0.f; }

    // prop1 + einsum term 0 (V hi+lo)
#pragma unroll
    for (int ks = 0; ks < 4; ks++) {
        s16x8 afr = *(const s16x8*)(LA + ((rg * 4 + ks) * 64 + lane) * 8);
        int kb = ks * 16 + kbb;
        s16x8 bf0 = *(const s16x8*)(TbB + (fh * 64 + nl) * TBS + kb);
        s16x8 bf1 = *(const s16x8*)(TbB + (fh * 64 + 32 + nl) * TBS + kb);
        d0 = MFMA(afr, bf0, d0);
        d1 = MFMA(afr, bf1, d1);
    }
#pragma unroll
    for (int ks = 0; ks < 8; ks++) {
        s16x8 ah = *(const s16x8*)(TbA + mrowA * TAS + ks * 16 + kbb);
        s16x8 bh0 = *(const s16x8*)(vh0 + ks * 512);
        s16x8 bl0 = *(const s16x8*)(vl0 + ks * 512);
        s16x8 bh1 = *(const s16x8*)(vh1 + ks * 512);
        s16x8 bl1 = *(const s16x8*)(vl1 + ks * 512);
        gacc0 = MFMA(ah, bh0, gacc0); gacc0 = MFMA(ah, bl0, gacc0);
        gacc1 = MFMA(ah, bh1, gacc1); gacc1 = MFMA(ah, bl1, gacc1);
    }
    __syncthreads();
#pragma unroll
    for (int r = 0; r < 16; r++) {
        int mrow = (r & 3) + 8 * (r >> 2) + 4 * khalf;
        int node = rg * 32 + mrow;
        int f0 = fh * 64 + nl, f1 = f0 + 32;
        us h0 = (us)f2bf_u(d0[r]);
        us h1 = (us)f2bf_u(d1[r]);
        Pa[node * TAS + f0] = h0;
        Pa[node * TAS + f1] = h1;
        TbB[f0 * TBS + node] = h0;
        TbB[f1 * TBS + node] = h1;
    }
    __syncthreads();

    // prop2 + einsum term 1 (V hi only — P1 already bf16-quantized)
#pragma unroll
    for (int r = 0; r < 16; r++) { d0[r] = 0.f; d1[r] = 0.f; }
#pragma unroll
    for (int ks = 0; ks < 4; ks++) {
        s16x8 afr = *(const s16x8*)(LA + ((rg * 4 + ks) * 64 + lane) * 8);
        int kb = ks * 16 + kbb;
        s16x8 bf0 = *(const s16x8*)(TbB + (fh * 64 + nl) * TBS + kb);
        s16x8 bf1 = *(const s16x8*)(TbB + (fh * 64 + 32 + nl) * TBS + kb);
        d0 = MFMA(afr, bf0, d0);
        d1 = MFMA(afr, bf1, d1);
    }
#pragma unroll
    for (int ks = 0; ks < 8; ks++) {
        s16x8 ah = *(const s16x8*)(Pa + mrowA * TAS + ks * 16 + kbb);
        s16x8 bh0 = *(const s16x8*)(vh0 + (8 + ks) * 512);
        s16x8 bh1 = *(const s16x8*)(vh1 + (8 + ks) * 512);
        gacc0 = MFMA(ah, bh0, gacc0);
        gacc1 = MFMA(ah, bh1, gacc1);
    }
    __syncthreads();
#pragma unroll
    for (int r = 0; r < 16; r++) {
        int mrow = (r & 3) + 8 * (r >> 2) + 4 * khalf;
        int node = rg * 32 + mrow;
        int f0 = fh * 64 + nl, f1 = f0 + 32;
        Pa[node * TAS + f0] = (us)f2bf_u(d0[r]);
        Pa[node * TAS + f1] = (us)f2bf_u(d1[r]);
    }
    __syncthreads();
    // einsum term 2 (V hi only)
#pragma unroll
    for (int ks = 0; ks < 8; ks++) {
        s16x8 ah = *(const s16x8*)(Pa + mrowA * TAS + ks * 16 + kbb);
        s16x8 bh0 = *(const s16x8*)(vh0 + (16 + ks) * 512);
        s16x8 bh1 = *(const s16x8*)(vh1 + (16 + ks) * 512);
        gacc0 = MFMA(ah, bh0, gacc0);
        gacc1 = MFMA(ah, bh1, gacc1);
    }

    int c0 = fh * 64 + nl, c1 = c0 + 32;
    float bv0 = bias[c0], bv1 = bias[c1];
    size_t gb = (size_t)g * 8192 + (size_t)rg * 4096;
#pragma unroll
    for (int r = 0; r < 16; r++) {
        int mrow = (r & 3) + 8 * (r >> 2) + 4 * khalf;
        float v0 = gacc0[r] + bv0; v0 = v0 > 0.f ? v0 : 0.f;
        float v1 = gacc1[r] + bv1; v1 = v1 > 0.f ? v1 : 0.f;
        Gh[gb + fragoff32(mrow, c0)] = (us)f2bf_u(v0);
        Gh[gb + fragoff32(mrow, c1)] = (us)f2bf_u(v1);
    }
}

// ---------------- kernel 3: tconv2 MFMA + gate (W hi-only, 32-row tiles, XCD-swizzled) ----
// (unchanged from round 11)
__global__ __launch_bounds__(128) void k_tc2(
    const us* __restrict__ Gh,
    const us* __restrict__ WTh,
    const float* __restrict__ tb1, const float* __restrict__ tb2, const float* __restrict__ tb3,
    us* __restrict__ T2)
{
    int tid = threadIdx.x;
    int lane = tid & 63;
    int w = tid >> 6;
    int nl = lane & 31;
    size_t laneoff = (size_t)lane * 8;
    int i = blockIdx.x;
    int vb = (i & 7) * 288 + (i >> 3);
    int bt36 = vb >> 1, ntile = vb & 1;
    int b = bt36 / TT2, t = bt36 % TT2;

    const us* A[3];
#pragma unroll
    for (int k3 = 0; k3 < 3; k3++)
        A[k3] = Gh + (size_t)(b * TT + t + k3) * 8192 + (size_t)ntile * 4096 + laneoff;
    const us* Bh[3];
#pragma unroll
    for (int g3 = 0; g3 < 3; g3++)
        Bh[g3] = WTh + (size_t)(g3 * 2 + w) * 12288 + laneoff;

    f32x16 aP, aQ, aR;
#pragma unroll
    for (int r = 0; r < 16; r++) { aP[r] = 0.f; aQ[r] = 0.f; aR[r] = 0.f; }

#pragma unroll
    for (int k3 = 0; k3 < 3; k3++) {
#pragma unroll
        for (int ls = 0; ls < 8; ls++) {
            int offB = (k3 * 8 + ls) * 512;
            s16x8 a0 = *(const s16x8*)(A[k3] + ls * 512);
            s16x8 ph = *(const s16x8*)(Bh[0] + offB);
            s16x8 qh = *(const s16x8*)(Bh[1] + offB);
            s16x8 rh = *(const s16x8*)(Bh[2] + offB);
            aP = MFMA(a0, ph, aP);
            aQ = MFMA(a0, qh, aQ);
            aR = MFMA(a0, rh, aR);
        }
    }

    int o = w * 32 + nl;
    float bP = tb1[o], bQ = tb2[o], bR = tb3[o];
    int rbase = (lane >> 5) * 4;
#pragma unroll
    for (int r = 0; r < 16; r++) {
        int m = (r & 3) + 8 * (r >> 2) + rbase;
        int node = ntile * 32 + m;
        if (node < NN) {
            float P = aP[r] + bP, Q = aQ[r] + bQ, R = aR[r] + bR;
            float sg = 1.f / (1.f + expf(-Q));
            float v = P * sg + R;
            v = v > 0.f ? v : 0.f;
            T2[((size_t)bt36 * NN + node) * CO + o] = (us)f2bf_u(v);
        }
    }
}

// ---------------- kernel 4: fused BN stats + windowed t-sums + conv3 GEMM + pool --------
// 100 blocks = 50 nodes x 2 j-halves. Phase A: node stats (coalesced 16B/lane reads).
// Phase B: sliding-window U into LDS with BN applied. Phase C: staged-W3 GEMM -> atomics.
#define UPST 129
__global__ __launch_bounds__(256) void k_upool(
    const us* __restrict__ T2,
    const float* __restrict__ gamma, const float* __restrict__ beta,
    const float* __restrict__ W3, float* __restrict__ pooled)
{
    __shared__ float Ws[96 * UPST];                  // 49,536 B
    __shared__ __align__(16) float Ul[96 * 36];      // 13,824 B
    __shared__ float red[512];
    int blk = blockIdx.x;            // n*2 + jh
    int n = blk >> 1, jh = blk & 1;
    int tid = threadIdx.x;

    // ---- phase 0: stage W3 slice (coalesced 128B reads, bank-safe LDS scatter) ----
    for (int i = tid; i < 12288; i += 256) {
        int ok = i >> 5, j = i & 31;
        int o = ok / 3, k = ok - 3 * o;
        Ws[(k * 32 + j) * UPST + o] = W3[(size_t)o * 9600 + k * 3200 + n * 64 + jh * 32 + j];
    }

    // ---- phase A: node stats (sum, sumsq over all 64 o, 32 b, 36 t) ----
    float s = 0.f, ss = 0.f;
    for (int i = tid; i < 9216; i += 256) {          // 1152 bt x 8 j8-groups
        int bt = i >> 3, j8 = i & 7;
        s16x8 v = *(const s16x8*)(T2 + (size_t)bt * 3200 + n * 64 + j8 * 8);
#pragma unroll
        for (int j = 0; j < 8; j++) {
            float f = bfu2f((us)v[j]);
            s += f; ss += f * f;
        }
    }
    red[tid] = s; red[256 + tid] = ss;
    __syncthreads();
    for (int off = 128; off > 0; off >>= 1) {
        if (tid < off) { red[tid] += red[tid + off]; red[256 + tid] += red[256 + tid + off]; }
        __syncthreads();
    }
    const float inv = 1.f / (float)(BB * TT2 * CO);
    float mn = red[0] * inv;
    float var = red[256] * inv - mn * mn;
    float sc = rsqrtf(var + 1e-5f) * gamma[n];
    float offv = (float)TPOOL * beta[n] - (float)TPOOL * mn * sc;
    __syncthreads();

    // ---- phase B: windowed t-sums for this block's 32 j-columns (L2-hot from phase A) ----
    for (int p = tid; p < 1024; p += 256) {          // 32 j x 32 b
        int j = p & 31, b = p >> 5;
        const us* q = T2 + (size_t)b * 115200 + n * 64 + jh * 32 + j;
        float s0 = 0.f;
        for (int t = 0; t < TPOOL; t++) s0 += bfu2f(q[(size_t)t * 3200]);
        float s1 = s0 - bfu2f(q[0]) + bfu2f(q[(size_t)34 * 3200]);
        float s2 = s1 - bfu2f(q[(size_t)1 * 3200]) + bfu2f(q[(size_t)35 * 3200]);
        Ul[(0 * 32 + j) * 36 + b] = s0 * sc + offv;
        Ul[(1 * 32 + j) * 36 + b] = s1 * sc + offv;
        Ul[(2 * 32 + j) * 36 + b] = s2 * sc + offv;
    }
    __syncthreads();

    // ---- phase C: GEMM 96 kj x 128 o x 32 b -> atomic accumulate into pooled ----
    int o = tid & 127, bq = tid >> 7;
    float acc[16];
#pragma unroll
    for (int i = 0; i < 16; i++) acc[i] = 0.f;
    for (int kj = 0; kj < 96; kj++) {
        float wv = Ws[kj * UPST + o];
        const float* up = &Ul[kj * 36 + bq * 16];
#pragma unroll
        for (int i4 = 0; i4 < 4; i4++) {
            float4 u = *(const float4*)(up + i4 * 4);
            acc[i4 * 4 + 0] += wv * u.x;
            acc[i4 * 4 + 1] += wv * u.y;
            acc[i4 * 4 + 2] += wv * u.z;
            acc[i4 * 4 + 3] += wv * u.w;
        }
    }
#pragma unroll
    for (int i = 0; i < 16; i++)
        atomicAdd(&pooled[(size_t)(bq * 16 + i) * 128 + o], acc[i]);
}

// ---------------- kernel 5: final FC (coalesced q-major, conv3 bias + 1/34 folded) -------
__global__ __launch_bounds__(256) void k_final(
    const float* __restrict__ pooled, const float* __restrict__ b3c,
    const float* __restrict__ f1w, const float* __restrict__ f1b,
    float* __restrict__ out)
{
    int idx = blockIdx.x * 256 + threadIdx.x;
    if (idx >= BB * NCO) return;
    int q = idx % NCO;
    int b = idx / NCO;
    const float inv = 1.f / (float)TPOOL;
    float acc = f1b[q];
    const float* pp = pooled + b * 128;
#pragma unroll 4
    for (int o = 0; o < 128; o++) acc += (pp[o] * inv + b3c[o]) * f1w[(size_t)o * NCO + q];
    out[idx] = acc;
}

// ---------------- launch ----------------
extern "C" void kernel_launch(void* const* d_in, const int* in_sizes, int n_in,
                              void* d_out, int out_size, void* d_ws, size_t ws_size,
                              hipStream_t stream)
{
    const float* X       = (const float*)d_in[0];
    const int*   EI      = (const int*)d_in[1];
    const float* tc1_w1  = (const float*)d_in[2];
    const float* tc1_b1  = (const float*)d_in[3];
    const float* tc1_w2  = (const float*)d_in[4];
    const float* tc1_b2  = (const float*)d_in[5];
    const float* tc1_w3  = (const float*)d_in[6];
    const float* tc1_b3  = (const float*)d_in[7];
    const float* cheb_w  = (const float*)d_in[8];
    const float* cheb_b  = (const float*)d_in[9];
    const float* tc2_w1  = (const float*)d_in[10];
    const float* tc2_b1  = (const float*)d_in[11];
    const float* tc2_w2  = (const float*)d_in[12];
    const float* tc2_b2  = (const float*)d_in[13];
    const float* tc2_w3  = (const float*)d_in[14];
    const float* tc2_b3  = (const float*)d_in[15];
    const float* bn_g    = (const float*)d_in[16];
    const float* bn_b    = (const float*)d_in[17];
    const float* conv3_w = (const float*)d_in[18];
    const float* conv3_b = (const float*)d_in[19];
    const float* f1_w    = (const float*)d_in[20];
    const float* f1_b    = (const float*)d_in[21];

    char* base = (char*)d_ws;
    us*    Gh     = (us*)base;                                   // 19,922,944 B
    us*    T2     = (us*)(base + PB_BYTES);                      // 7,372,800 B (bf16)
    float* pooled = (float*)(base + PB_BYTES + 7372800);         // 16,384 B
    us*    VTh    = (us*)(base + PB_BYTES + 7389184);
    us*    VTl    = VTh + 49152;
    us*    WTh    = VTl + 49152;

    k_wprep<<<496, 256, 0, stream>>>(cheb_w, tc2_w1, tc2_w2, tc2_w3, VTh, VTl, WTh, pooled);
    k_cheb<<<SS, 256, 0, stream>>>(EI, X, tc1_w1, tc1_b1, tc1_w2, tc1_b2, tc1_w3, tc1_b3,
                                   VTh, VTl, cheb_b, Gh);
    k_tc2<<<2304, 128, 0, stream>>>(Gh, WTh, tc2_b1, tc2_b2, tc2_b3, T2);
    k_upool<<<100, 256, 0, stream>>>(T2, bn_g, bn_b, conv3_w, pooled);
    k_final<<<(BB * NCO + 255) / 256, 256, 0, stream>>>(pooled, conv3_b, f1_w, f1_b, (float*)d_out);
}

// Round 13
// 211.825 us; speedup vs baseline: 1.0485x; 1.0485x over previous
//
#include <hip/hip_runtime.h>
#include <hip/hip_bf16.h>

// ---------------- sizes ----------------
#define BB 32
#define TW 40
#define NN 50
#define HH 128
#define CO 64
#define EE 800
#define TT 38      // Tw - 2
#define TT2 36     // TT - 2
#define TPOOL 34   // TT2 - 2
#define NCO 3200   // N*Co
#define SS (BB*TT)     // 1216 graphs
#define NPAD 64
#define RPAD (SS*NPAD)

// fragment-major G plane: addr(node,feat) = g*8192 + (node>>5)*4096 + (feat>>4)*512
//                                         + ((feat>>3)&1)*256 + (node&31)*8 + (feat&7)
#define PB_US ((size_t)RPAD * HH)
#define PB_BYTES (PB_US * 2)          // 19,922,944

typedef __attribute__((ext_vector_type(8))) short s16x8;
typedef __attribute__((ext_vector_type(16))) float f32x16;
typedef unsigned short us;

static __device__ __forceinline__ unsigned int f2bf_u(float x) {
    unsigned int u = __float_as_uint(x);
    return (u + 0x7fffu + ((u >> 16) & 1u)) >> 16;
}
static __device__ __forceinline__ float bfu2f(unsigned int h) {
    return __uint_as_float(h << 16);
}
static __device__ __forceinline__ size_t fragoff32(int m, int c) {  // m<32
    return (size_t)(c >> 4) * 512 + ((c >> 3) & 1) * 256 + m * 8 + (c & 7);
}
#define MFMA(a, b, c) __builtin_amdgcn_mfma_f32_32x32x16_bf16((a), (b), (c), 0, 0, 0)

// ---------------- kernel 1: weight prep + Laplacian fragment build ----------------
// blocks 0..495: V/W weight prep + zero pooled. blocks 496..1711: per-graph L -> LA frags.
__global__ __launch_bounds__(256) void k_prep(
    const float* __restrict__ cw,
    const float* __restrict__ tw1, const float* __restrict__ tw2, const float* __restrict__ tw3,
    const int* __restrict__ EI,
    us* __restrict__ VTh, us* __restrict__ WTh,
    us* __restrict__ LAg, float* __restrict__ pooled)
{
    __shared__ float Lm[50 * 51];
    __shared__ int   deg[NN];
    __shared__ float dis[NN];
    int blk = blockIdx.x;
    int tid = threadIdx.x;

    if (blk < 496) {
        int idx = blk * 256 + tid;
        float v; int col, k; us* dh;
        if (idx < 128 * 384) {
            col = idx / 384; k = idx % 384;
            if (k < 128)      v = cw[k * 128 + col] - cw[32768 + k * 128 + col];
            else if (k < 256) v = cw[16384 + (k - 128) * 128 + col];
            else              v = 2.f * cw[32768 + (k - 256) * 128 + col];
            dh = VTh;
        } else if (idx < 128 * 384 + 192 * 384) {
            int i2 = idx - 128 * 384;
            col = i2 / 384; k = i2 % 384;
            int gg = col >> 6, o = col & 63;
            const float* src = (gg == 0) ? tw1 : (gg == 1) ? tw2 : tw3;
            v = src[k * 64 + o];
            dh = WTh;
        } else {
            int z = idx - (128 * 384 + 192 * 384);
            if (z < 4096) pooled[z] = 0.f;
            return;
        }
        size_t off = ((size_t)((col >> 5) * 24 + (k >> 4)) * 64 + ((k >> 3) & 1) * 32 + (col & 31)) * 8
                   + (k & 7);
        dh[off] = (us)f2bf_u(v);
    } else {
        int g = blk - 496;
        int b = g / TT, t = g % TT;
        const int* row = EI + (size_t)(b * TW + t) * 2 * EE;
        const int* col = row + EE;
        for (int i = tid; i < 50 * 51; i += 256) Lm[i] = 0.f;
        if (tid < NN) deg[tid] = 0;
        __syncthreads();
        for (int e = tid; e < EE; e += 256) atomicAdd(&deg[row[e]], 1);
        __syncthreads();
        if (tid < NN) dis[tid] = deg[tid] > 0 ? rsqrtf((float)deg[tid]) : 0.f;
        __syncthreads();
        for (int e = tid; e < EE; e += 256) {
            int r = row[e], cc = col[e];
            atomicAdd(&Lm[r * 51 + cc], -dis[r] * dis[cc]);
        }
        __syncthreads();
        for (int ent = tid; ent < 512; ent += 256) {
            int lanee = ent & 63;
            int ks = (ent >> 6) & 3;
            int mt = ent >> 8;
            int m = mt * 32 + (lanee & 31);
            int kb = ks * 16 + (lanee >> 5) * 8;
            s16x8 v;
#pragma unroll
            for (int j = 0; j < 8; j++) {
                int k = kb + j;
                float lv = (m < NN && k < NN) ? Lm[m * 51 + k] : 0.f;
                v[j] = (short)f2bf_u(lv);
            }
            *(s16x8*)(LAg + (size_t)g * 4096 + ent * 8) = v;
        }
    }
}

// ---------------- kernel 2: fused tconv1 + Cheb prop + einsum (LA from global) ----------
// LDS 53,248 B. 6 barriers (L-build hoisted to k_prep). V hi-only everywhere.
#define TAS 136
#define TBS 72
__global__ __launch_bounds__(256) void k_cheb(
    const float* __restrict__ X,
    const float* __restrict__ w1, const float* __restrict__ b1,
    const float* __restrict__ w2, const float* __restrict__ b2,
    const float* __restrict__ w3, const float* __restrict__ b3,
    const us* __restrict__ VTh, const us* __restrict__ LAg,
    const float* __restrict__ bias,
    us* __restrict__ Gh)
{
    __shared__ __align__(16) char smem[53248];
    us* TbA = (us*)smem;                       // 64*136 us (T0-A)
    us* TbB = (us*)(smem + 17408);             // 128*72 us (T0-B, then P1-B)
    us* Pa  = (us*)(smem + 35840);             // 64*136 us (P1-A, then P2-A)
    float* Xs = (float*)(smem + 35840);        // 1200 B overlay (dead before P1 write)

    int g = blockIdx.x;
    int tid = threadIdx.x;
    int b = g / TT, t = g % TT;

    {
        s16x8 zz = {0, 0, 0, 0, 0, 0, 0, 0};
        for (int i = tid; i < 2240; i += 256) ((s16x8*)smem)[i] = zz;
    }
    for (int i = tid; i < 300; i += 256) Xs[i] = X[(size_t)(b * TW + t) * 100 + i];
    __syncthreads();

    // tconv1 -> TbA (A-layout hi) + TbB (B-layout hi)
    {
        int c = tid & 127, nh = tid >> 7;
        float wr1[6], wr2[6], wr3[6];
#pragma unroll
        for (int q = 0; q < 6; q++) {
            wr1[q] = w1[q * HH + c];
            wr2[q] = w2[q * HH + c];
            wr3[q] = w3[q * HH + c];
        }
        float bv1 = b1[c], bv2 = b2[c], bv3 = b3[c];
        for (int n = nh; n < NN; n += 2) {
            float P = bv1, Q = bv2, R = bv3;
#pragma unroll
            for (int q = 0; q < 6; q++) {
                float x = Xs[(q >> 1) * 100 + n * 2 + (q & 1)];
                P += x * wr1[q]; Q += x * wr2[q]; R += x * wr3[q];
            }
            float sg = 1.f / (1.f + expf(-Q));
            float v = P * sg + R;
            v = v > 0.f ? v : 0.f;
            us h = (us)f2bf_u(v);
            TbA[n * TAS + c] = h;
            TbB[c * TBS + n] = h;
        }
    }
    __syncthreads();

    int lane = tid & 63;
    int w = tid >> 6;
    int rg = w >> 1, fh = w & 1;
    int nl = lane & 31;
    int khalf = lane >> 5;
    size_t laneoff = (size_t)lane * 8;

    const us* vh0 = VTh + (size_t)(fh * 2) * 12288 + laneoff;
    const us* vh1 = VTh + (size_t)(fh * 2 + 1) * 12288 + laneoff;
    const us* lag = LAg + (size_t)g * 4096 + (size_t)rg * 2048 + laneoff;

    int mrowA = rg * 32 + nl;
    int kbb = khalf * 8;

    f32x16 gacc0, gacc1, d0, d1;
#pragma unroll
    for (int r = 0; r < 16; r++) { gacc0[r] = 0.f; gacc1[r] = 0.f; d0[r] = 0.f; d1[r] = 0.f; }

    // prop1 (P1 = L@T0) + einsum term 0
#pragma unroll
    for (int ks = 0; ks < 4; ks++) {
        s16x8 afr = *(const s16x8*)(lag + ks * 512);
        int kb = ks * 16 + kbb;
        s16x8 bf0 = *(const s16x8*)(TbB + (fh * 64 + nl) * TBS + kb);
        s16x8 bf1 = *(const s16x8*)(TbB + (fh * 64 + 32 + nl) * TBS + kb);
        d0 = MFMA(afr, bf0, d0);
        d1 = MFMA(afr, bf1, d1);
    }
#pragma unroll
    for (int ks = 0; ks < 8; ks++) {
        s16x8 ah = *(const s16x8*)(TbA + mrowA * TAS + ks * 16 + kbb);
        s16x8 bh0 = *(const s16x8*)(vh0 + ks * 512);
        s16x8 bh1 = *(const s16x8*)(vh1 + ks * 512);
        gacc0 = MFMA(ah, bh0, gacc0);
        gacc1 = MFMA(ah, bh1, gacc1);
    }
    __syncthreads();   // all TbA/TbB reads done before P1 writes
#pragma unroll
    for (int r = 0; r < 16; r++) {
        int mrow = (r & 3) + 8 * (r >> 2) + 4 * khalf;
        int node = rg * 32 + mrow;
        int f0 = fh * 64 + nl, f1 = f0 + 32;
        us h0 = (us)f2bf_u(d0[r]);
        us h1 = (us)f2bf_u(d1[r]);
        Pa[node * TAS + f0] = h0;
        Pa[node * TAS + f1] = h1;
        TbB[f0 * TBS + node] = h0;
        TbB[f1 * TBS + node] = h1;
    }
    __syncthreads();

    // prop2 (P2 = L@P1) + einsum term 1 (A = P1)
#pragma unroll
    for (int r = 0; r < 16; r++) { d0[r] = 0.f; d1[r] = 0.f; }
#pragma unroll
    for (int ks = 0; ks < 4; ks++) {
        s16x8 afr = *(const s16x8*)(lag + ks * 512);
        int kb = ks * 16 + kbb;
        s16x8 bf0 = *(const s16x8*)(TbB + (fh * 64 + nl) * TBS + kb);
        s16x8 bf1 = *(const s16x8*)(TbB + (fh * 64 + 32 + nl) * TBS + kb);
        d0 = MFMA(afr, bf0, d0);
        d1 = MFMA(afr, bf1, d1);
    }
#pragma unroll
    for (int ks = 0; ks < 8; ks++) {
        s16x8 ah = *(const s16x8*)(Pa + mrowA * TAS + ks * 16 + kbb);
        s16x8 bh0 = *(const s16x8*)(vh0 + (8 + ks) * 512);
        s16x8 bh1 = *(const s16x8*)(vh1 + (8 + ks) * 512);
        gacc0 = MFMA(ah, bh0, gacc0);
        gacc1 = MFMA(ah, bh1, gacc1);
    }
    __syncthreads();   // Pa/TbB reads done before P2 writes
#pragma unroll
    for (int r = 0; r < 16; r++) {
        int mrow = (r & 3) + 8 * (r >> 2) + 4 * khalf;
        int node = rg * 32 + mrow;
        int f0 = fh * 64 + nl, f1 = f0 + 32;
        Pa[node * TAS + f0] = (us)f2bf_u(d0[r]);
        Pa[node * TAS + f1] = (us)f2bf_u(d1[r]);
    }
    __syncthreads();
    // einsum term 2 (A = P2)
#pragma unroll
    for (int ks = 0; ks < 8; ks++) {
        s16x8 ah = *(const s16x8*)(Pa + mrowA * TAS + ks * 16 + kbb);
        s16x8 bh0 = *(const s16x8*)(vh0 + (16 + ks) * 512);
        s16x8 bh1 = *(const s16x8*)(vh1 + (16 + ks) * 512);
        gacc0 = MFMA(ah, bh0, gacc0);
        gacc1 = MFMA(ah, bh1, gacc1);
    }

    int c0 = fh * 64 + nl, c1 = c0 + 32;
    float bv0 = bias[c0], bv1 = bias[c1];
    size_t gb = (size_t)g * 8192 + (size_t)rg * 4096;
#pragma unroll
    for (int r = 0; r < 16; r++) {
        int mrow = (r & 3) + 8 * (r >> 2) + 4 * khalf;
        float v0 = gacc0[r] + bv0; v0 = v0 > 0.f ? v0 : 0.f;
        float v1 = gacc1[r] + bv1; v1 = v1 > 0.f ? v1 : 0.f;
        Gh[gb + fragoff32(mrow, c0)] = (us)f2bf_u(v0);
        Gh[gb + fragoff32(mrow, c1)] = (us)f2bf_u(v1);
    }
}

// ---------------- kernel 3: tconv2 MFMA + gate (unchanged from round 11/12) ----------------
__global__ __launch_bounds__(128) void k_tc2(
    const us* __restrict__ Gh,
    const us* __restrict__ WTh,
    const float* __restrict__ tb1, const float* __restrict__ tb2, const float* __restrict__ tb3,
    us* __restrict__ T2)
{
    int tid = threadIdx.x;
    int lane = tid & 63;
    int w = tid >> 6;
    int nl = lane & 31;
    size_t laneoff = (size_t)lane * 8;
    int i = blockIdx.x;
    int vb = (i & 7) * 288 + (i >> 3);
    int bt36 = vb >> 1, ntile = vb & 1;
    int b = bt36 / TT2, t = bt36 % TT2;

    const us* A[3];
#pragma unroll
    for (int k3 = 0; k3 < 3; k3++)
        A[k3] = Gh + (size_t)(b * TT + t + k3) * 8192 + (size_t)ntile * 4096 + laneoff;
    const us* Bh[3];
#pragma unroll
    for (int g3 = 0; g3 < 3; g3++)
        Bh[g3] = WTh + (size_t)(g3 * 2 + w) * 12288 + laneoff;

    f32x16 aP, aQ, aR;
#pragma unroll
    for (int r = 0; r < 16; r++) { aP[r] = 0.f; aQ[r] = 0.f; aR[r] = 0.f; }

#pragma unroll
    for (int k3 = 0; k3 < 3; k3++) {
#pragma unroll
        for (int ls = 0; ls < 8; ls++) {
            int offB = (k3 * 8 + ls) * 512;
            s16x8 a0 = *(const s16x8*)(A[k3] + ls * 512);
            s16x8 ph = *(const s16x8*)(Bh[0] + offB);
            s16x8 qh = *(const s16x8*)(Bh[1] + offB);
            s16x8 rh = *(const s16x8*)(Bh[2] + offB);
            aP = MFMA(a0, ph, aP);
            aQ = MFMA(a0, qh, aQ);
            aR = MFMA(a0, rh, aR);
        }
    }

    int o = w * 32 + nl;
    float bP = tb1[o], bQ = tb2[o], bR = tb3[o];
    int rbase = (lane >> 5) * 4;
#pragma unroll
    for (int r = 0; r < 16; r++) {
        int m = (r & 3) + 8 * (r >> 2) + rbase;
        int node = ntile * 32 + m;
        if (node < NN) {
            float P = aP[r] + bP, Q = aQ[r] + bQ, R = aR[r] + bR;
            float sg = 1.f / (1.f + expf(-Q));
            float v = P * sg + R;
            v = v > 0.f ? v : 0.f;
            T2[((size_t)bt36 * NN + node) * CO + o] = (us)f2bf_u(v);
        }
    }
}

// ---------------- kernel 4: fused BN stats + windowed t-sums + conv3 GEMM + pool --------
// 400 blocks = 50 n x 2 jh x 4 b-quarters. Stats recomputed per block (L2-hot).
#define UPST 129
__global__ __launch_bounds__(256) void k_upool(
    const us* __restrict__ T2,
    const float* __restrict__ gamma, const float* __restrict__ beta,
    const float* __restrict__ W3, float* __restrict__ pooled)
{
    __shared__ float Ws[96 * UPST];                  // 49,536 B
    __shared__ __align__(16) float Ul[96 * 12];      // 4,608 B
    __shared__ float red[512];
    int blk = blockIdx.x;
    int n = blk >> 3;
    int jh = (blk >> 2) & 1;
    int bq = blk & 3;
    int tid = threadIdx.x;

    // stage W3 slice for (n, jh)
    for (int i = tid; i < 12288; i += 256) {
        int ok = i >> 5, j = i & 31;
        int o = ok / 3, k = ok - 3 * o;
        Ws[(k * 32 + j) * UPST + o] = W3[(size_t)o * 9600 + k * 3200 + n * 64 + jh * 32 + j];
    }

    // node stats (coalesced 16B/lane over the full node slice)
    float s = 0.f, ss = 0.f;
    for (int i = tid; i < 9216; i += 256) {
        int bt = i >> 3, j8 = i & 7;
        s16x8 v = *(const s16x8*)(T2 + (size_t)bt * 3200 + n * 64 + j8 * 8);
#pragma unroll
        for (int j = 0; j < 8; j++) {
            float f = bfu2f((us)v[j]);
            s += f; ss += f * f;
        }
    }
    red[tid] = s; red[256 + tid] = ss;
    __syncthreads();
    for (int off = 128; off > 0; off >>= 1) {
        if (tid < off) { red[tid] += red[tid + off]; red[256 + tid] += red[256 + tid + off]; }
        __syncthreads();
    }
    const float inv = 1.f / (float)(BB * TT2 * CO);
    float mn = red[0] * inv;
    float var = red[256] * inv - mn * mn;
    float sc = rsqrtf(var + 1e-5f) * gamma[n];
    float offv = (float)TPOOL * beta[n] - (float)TPOOL * mn * sc;
    __syncthreads();

    // windowed t-sums: 32 j x 8 b (one per thread)
    {
        int j = tid & 31, bl = tid >> 5;             // bl 0..7
        int bb = bq * 8 + bl;
        const us* q = T2 + (size_t)bb * 115200 + n * 64 + jh * 32 + j;
        float s0 = 0.f;
        for (int t = 0; t < TPOOL; t++) s0 += bfu2f(q[(size_t)t * 3200]);
        float s1 = s0 - bfu2f(q[0]) + bfu2f(q[(size_t)34 * 3200]);
        float s2 = s1 - bfu2f(q[(size_t)1 * 3200]) + bfu2f(q[(size_t)35 * 3200]);
        Ul[(0 * 32 + j) * 12 + bl] = s0 * sc + offv;
        Ul[(1 * 32 + j) * 12 + bl] = s1 * sc + offv;
        Ul[(2 * 32 + j) * 12 + bl] = s2 * sc + offv;
    }
    __syncthreads();

    // GEMM 96 kj x 128 o x 8 b -> atomic accumulate
    int o = tid & 127, bq2 = tid >> 7;               // bq2 0..1 -> b-locals 4
    float acc[4] = {0.f, 0.f, 0.f, 0.f};
    for (int kj = 0; kj < 96; kj++) {
        float wv = Ws[kj * UPST + o];
        float4 u = *(const float4*)&Ul[kj * 12 + bq2 * 4];
        acc[0] += wv * u.x;
        acc[1] += wv * u.y;
        acc[2] += wv * u.z;
        acc[3] += wv * u.w;
    }
#pragma unroll
    for (int i = 0; i < 4; i++)
        atomicAdd(&pooled[(size_t)(bq * 8 + bq2 * 4 + i) * 128 + o], acc[i]);
}

// ---------------- kernel 5: final FC (coalesced q-major, conv3 bias + 1/34 folded) -------
__global__ __launch_bounds__(256) void k_final(
    const float* __restrict__ pooled, const float* __restrict__ b3c,
    const float* __restrict__ f1w, const float* __restrict__ f1b,
    float* __restrict__ out)
{
    int idx = blockIdx.x * 256 + threadIdx.x;
    if (idx >= BB * NCO) return;
    int q = idx % NCO;
    int b = idx / NCO;
    const float inv = 1.f / (float)TPOOL;
    float acc = f1b[q];
    const float* pp = pooled + b * 128;
#pragma unroll 4
    for (int o = 0; o < 128; o++) acc += (pp[o] * inv + b3c[o]) * f1w[(size_t)o * NCO + q];
    out[idx] = acc;
}

// ---------------- launch ----------------
extern "C" void kernel_launch(void* const* d_in, const int* in_sizes, int n_in,
                              void* d_out, int out_size, void* d_ws, size_t ws_size,
                              hipStream_t stream)
{
    const float* X       = (const float*)d_in[0];
    const int*   EI      = (const int*)d_in[1];
    const float* tc1_w1  = (const float*)d_in[2];
    const float* tc1_b1  = (const float*)d_in[3];
    const float* tc1_w2  = (const float*)d_in[4];
    const float* tc1_b2  = (const float*)d_in[5];
    const float* tc1_w3  = (const float*)d_in[6];
    const float* tc1_b3  = (const float*)d_in[7];
    const float* cheb_w  = (const float*)d_in[8];
    const float* cheb_b  = (const float*)d_in[9];
    const float* tc2_w1  = (const float*)d_in[10];
    const float* tc2_b1  = (const float*)d_in[11];
    const float* tc2_w2  = (const float*)d_in[12];
    const float* tc2_b2  = (const float*)d_in[13];
    const float* tc2_w3  = (const float*)d_in[14];
    const float* tc2_b3  = (const float*)d_in[15];
    const float* bn_g    = (const float*)d_in[16];
    const float* bn_b    = (const float*)d_in[17];
    const float* conv3_w = (const float*)d_in[18];
    const float* conv3_b = (const float*)d_in[19];
    const float* f1_w    = (const float*)d_in[20];
    const float* f1_b    = (const float*)d_in[21];

    char* base = (char*)d_ws;
    us*    Gh     = (us*)base;                                   // 19,922,944 B
    us*    T2     = (us*)(base + PB_BYTES);                      // 7,372,800 B (bf16)
    float* pooled = (float*)(base + PB_BYTES + 7372800);         // 16,384 B
    us*    VTh    = (us*)(base + PB_BYTES + 7389184);            // 98,304 B
    us*    WTh    = VTh + 49152;                                 // 147,456 B
    us*    LAg    = WTh + 73728;                                 // 9,961,472 B

    k_prep<<<496 + SS, 256, 0, stream>>>(cheb_w, tc2_w1, tc2_w2, tc2_w3, EI, VTh, WTh, LAg, pooled);
    k_cheb<<<SS, 256, 0, stream>>>(X, tc1_w1, tc1_b1, tc1_w2, tc1_b2, tc1_w3, tc1_b3,
                                   VTh, LAg, cheb_b, Gh);
    k_tc2<<<2304, 128, 0, stream>>>(Gh, WTh, tc2_b1, tc2_b2, tc2_b3, T2);
    k_upool<<<400, 256, 0, stream>>>(T2, bn_g, bn_b, conv3_w, pooled);
    k_final<<<(BB * NCO + 255) / 256, 256, 0, stream>>>(pooled, conv3_b, f1_w, f1_b, (float*)d_out);
}